// Round 4
// baseline (209.595 us; speedup 1.0000x reference)
//
#include <hip/hip_runtime.h>
#include <hip/hip_cooperative_groups.h>

namespace cg = cooperative_groups;

// HebbianNet fused: 3 layers in ONE cooperative kernel, grid.sync() between.
// Per-layer identity (conv1->conv2 with no nonlinearity is affine in
// (vi, w, vj)):
//   out[b,o] = vj + r*(a0*Sum_i v^2 + a1*dot[b,o] + (a2*vj + cc)*Sum_i v)
//   dot = v@W^T (pre-bias), vj = relu(dot + bias),
//   a_c = sum_h cw2[h]*cw1[h][c], cc = sum_h cw2[h]*cb1[h] + cb2,
//   r = RATE/batch_num.
// R4: fuse 3 launches -> 1 cooperative launch (removes 2 launch overheads +
// 2 HBM-latency ramps). R2/R3 showed ~82us of dur_us is harness d_ws
// re-poison (2x 268MB fills @ 40us); this targets the ~15-18us controllable
// slice.

#define RATE_F 0.001f
constexpr int NIN   = 1024;
constexpr int BATCH = 8;

struct Smem {
    float vsh[BATCH * NIN];   // 32 KB staged activations
    float coeff[8];           // a0,a1,a2,cc,rate
    float svs[BATCH], s2s[BATCH];
};

// One layer phase. Block = 256 threads = 4 waves; wave w computes output row
// o = blockIdx.x*rpb + w (w < rpb) for all 8 batches. Caller grid-syncs
// between phases.
__device__ __forceinline__ void hebb_phase(
    const float* __restrict__ vin,   // (8, 1024)
    const float* __restrict__ W,     // (n_out, 1024)
    const float* __restrict__ bias,  // (n_out,)
    float*       __restrict__ vout,  // (8, n_out)
    int n_out, int rpb, Smem& sm)
{
    const int tid  = threadIdx.x;
    const int w    = tid >> 6, lane = tid & 63;
    const int o    = blockIdx.x * rpb + w;
    const bool active = (w < rpb);

    // ---- issue W-row + bias loads first (latency overlaps staging/sums) ----
    const int i0a = lane * 8;          // floats [i0a, i0a+8)
    const int i0b = 512 + lane * 8;
    float4 w0, w1, w2, w3;
    float  bo = 0.f;
    if (active) {
        const float4* Wrow = (const float4*)(W + (size_t)o * NIN);
        w0 = Wrow[(i0a >> 2) + 0];
        w1 = Wrow[(i0a >> 2) + 1];
        w2 = Wrow[(i0b >> 2) + 0];
        w3 = Wrow[(i0b >> 2) + 1];
        bo = bias[o];
    }

    // ---- stage input into LDS ----
    {
        const float4* p = (const float4*)vin;   // 8192 f32 = 2048 float4
        for (int k = tid; k < 2048; k += 256)
            *(float4*)&sm.vsh[k * 4] = p[k];
    }
    __syncthreads();

    // ---- per-batch sum(v), sum(v^2) ----
    {
        int b = tid >> 5, j = tid & 31;        // 32 threads per batch row
        float sv = 0.f, s2 = 0.f;
        for (int i = j; i < NIN; i += 32) {
            float v = sm.vsh[b * NIN + i];
            sv += v; s2 += v * v;
        }
        #pragma unroll
        for (int m = 16; m >= 1; m >>= 1) {    // stays within 32-lane halves
            sv += __shfl_xor(sv, m, 64);
            s2 += __shfl_xor(s2, m, 64);
        }
        if (j == 0) { sm.svs[b] = sv; sm.s2s[b] = s2; }
    }
    __syncthreads();

    if (!active) return;   // exits phase only; caller's grid.sync still hit

    // ---- dots: wave per output row, W already in registers ----
    float acc[BATCH] = {0.f, 0.f, 0.f, 0.f, 0.f, 0.f, 0.f, 0.f};
    #pragma unroll
    for (int b = 0; b < BATCH; b++) {
        const float4 v0 = *(const float4*)&sm.vsh[b * NIN + i0a];
        const float4 v1 = *(const float4*)&sm.vsh[b * NIN + i0a + 4];
        const float4 v2 = *(const float4*)&sm.vsh[b * NIN + i0b];
        const float4 v3 = *(const float4*)&sm.vsh[b * NIN + i0b + 4];
        acc[b] += w0.x * v0.x + w0.y * v0.y + w0.z * v0.z + w0.w * v0.w
                + w1.x * v1.x + w1.y * v1.y + w1.z * v1.z + w1.w * v1.w
                + w2.x * v2.x + w2.y * v2.y + w2.z * v2.z + w2.w * v2.w
                + w3.x * v3.x + w3.y * v3.y + w3.z * v3.z + w3.w * v3.w;
    }
    #pragma unroll
    for (int b = 0; b < BATCH; b++) {
        #pragma unroll
        for (int m = 32; m >= 1; m >>= 1)
            acc[b] += __shfl_xor(acc[b], m, 64);
    }

    if (lane < BATCH) {
        const int b = lane;
        const float dot = acc[b];
        float vj = dot + bo;
        vj = vj > 0.f ? vj : 0.f;
        const float r = sm.coeff[4];
        const float outv = vj + r * (sm.coeff[0] * sm.s2s[b] + sm.coeff[1] * dot
                                     + (sm.coeff[2] * vj + sm.coeff[3]) * sm.svs[b]);
        vout[(size_t)b * n_out + o] = outv;
    }
}

__global__ __launch_bounds__(256, 1) void hebb_fused(
    const float* __restrict__ x,
    const float* __restrict__ W1, const float* __restrict__ b1,
    const float* __restrict__ W2, const float* __restrict__ b2,
    const float* __restrict__ W3, const float* __restrict__ b3,
    const float* __restrict__ cw1, const float* __restrict__ cb1,
    const float* __restrict__ cw2, const float* __restrict__ cb2,
    const int*   __restrict__ batch_num,
    float* __restrict__ v1, float* __restrict__ v2,
    float* __restrict__ out)
{
    __shared__ Smem sm;
    cg::grid_group grid = cg::this_grid();

    if (threadIdx.x == 0) {   // coeffs once; phase-1's first barrier publishes
        float a0 = 0.f, a1 = 0.f, a2 = 0.f, cc = 0.f;
        #pragma unroll
        for (int h = 0; h < 8; h++) {
            float c2 = cw2[h];
            a0 += c2 * cw1[h * 3 + 0];
            a1 += c2 * cw1[h * 3 + 1];
            a2 += c2 * cw1[h * 3 + 2];
            cc += c2 * cb1[h];
        }
        cc += cb2[0];
        sm.coeff[0] = a0; sm.coeff[1] = a1; sm.coeff[2] = a2; sm.coeff[3] = cc;
        sm.coeff[4] = RATE_F / (float)batch_num[0];
    }

    hebb_phase(x,  W1, b1, v1,  1024, 4, sm);   // blocks 0..255, 4 rows each
    __threadfence();
    grid.sync();
    hebb_phase(v1, W2, b2, v2,  1024, 4, sm);
    __threadfence();
    grid.sync();
    hebb_phase(v2, W3, b3, out,  512, 2, sm);   // 2 rows each across 256 blocks
}

extern "C" void kernel_launch(void* const* d_in, const int* in_sizes, int n_in,
                              void* d_out, int out_size, void* d_ws, size_t ws_size,
                              hipStream_t stream) {
    const float* x   = (const float*)d_in[0];
    const float* W1  = (const float*)d_in[1];
    const float* b1  = (const float*)d_in[2];
    const float* W2  = (const float*)d_in[3];
    const float* b2  = (const float*)d_in[4];
    const float* W3  = (const float*)d_in[5];
    const float* b3  = (const float*)d_in[6];
    const float* cw1 = (const float*)d_in[7];
    const float* cb1 = (const float*)d_in[8];
    const float* cw2 = (const float*)d_in[9];
    const float* cb2 = (const float*)d_in[10];
    const int*   bn  = (const int*)d_in[11];

    float* v1  = (float*)d_ws;        // 8x1024 fp32 intermediate
    float* v2  = v1 + 8 * 1024;       // 8x1024 fp32 intermediate
    float* out = (float*)d_out;

    void* args[] = { (void*)&x, (void*)&W1, (void*)&b1, (void*)&W2, (void*)&b2,
                     (void*)&W3, (void*)&b3, (void*)&cw1, (void*)&cb1,
                     (void*)&cw2, (void*)&cb2, (void*)&bn,
                     (void*)&v1, (void*)&v2, (void*)&out };
    hipLaunchCooperativeKernel((void*)hebb_fused, dim3(256), dim3(256),
                               args, 0, stream);
}

// Round 5
// 100.073 us; speedup vs baseline: 2.0944x; 2.0944x over previous
//
#include <hip/hip_runtime.h>

// HebbianNet: 3x (GEMV layer + linearized hebbian shift). ALL FP32.
// conv1(1x1,3->MH) -> conv2(1x1,MH->1) with no nonlinearity is affine in
// (vi, w, vj):
//   out[b,o] = vj + r*(a0*Sum_i v^2 + a1*dot[b,o] + (a2*vj + cc)*Sum_i v)
//   dot = v@W^T (pre-bias), vj = relu(dot + bias),
//   a_c = sum_h cw2[h]*cw1[h][c], cc = sum_h cw2[h]*cb1[h] + cb2,
//   r = RATE/batch_num.
//
// R5: LDS-free. R4 exposed SQ_LDS_BANK_CONFLICT=4.6M cycles (~7.5us/CU-avg)
// from the 8-float lane stride in vsh (16-way conflicts on ds_read_b128).
// Each lane only needs 16 v-floats per batch, and those same registers
// wave-reduce to Sum(v)/Sum(v^2) (lane word-ranges tile [0,1024) exactly).
// So: v straight from global (32KB, L1/L2-hot), dot + sums in registers,
// butterfly shuffles, no __syncthreads, no LDS arrays at all.
// (R4 also proved cooperative grid.sync costs ~50us/sync here -- reverted
// to 3 ordinary dependent launches.)

#define RATE_F 0.001f

// Block = 256 = 4 waves; wave w computes output row o = blockIdx.x*4 + w
// for all 8 batches. n_in fixed at 1024. Grid sized so o < n_out always.
__global__ __launch_bounds__(256) void hebb_layer(
    const float* __restrict__ vin,   // (8, 1024)
    const float* __restrict__ W,     // (n_out, 1024)
    const float* __restrict__ bias,  // (n_out,)
    const float* __restrict__ cw1,   // (8,3)
    const float* __restrict__ cb1,   // (8,)
    const float* __restrict__ cw2,   // (1,8)
    const float* __restrict__ cb2,   // (1,)
    const int*   __restrict__ batch_num,
    float*       __restrict__ vout,  // (8, n_out)
    int n_out)
{
    const int tid  = threadIdx.x;
    const int lane = tid & 63;
    const int o    = blockIdx.x * 4 + (tid >> 6);

    // ---- W row (HBM-cold): issue first so latency overlaps everything ----
    const float4* Wrow = (const float4*)(W + (size_t)o * 1024);
    const int ia = lane * 2;         // float4 idx, words [lane*8, lane*8+8)
    const int ib = 128 + lane * 2;   // words [512+lane*8, ...+8)
    const float4 w0 = Wrow[ia], w1 = Wrow[ia + 1];
    const float4 w2 = Wrow[ib], w3 = Wrow[ib + 1];
    const float  bo = bias[o];

    // ---- coefficients (uniform scalar loads, redundant per thread) ----
    float a0 = 0.f, a1 = 0.f, a2 = 0.f, cc = 0.f;
    #pragma unroll
    for (int h = 0; h < 8; h++) {
        const float c2 = cw2[h];
        a0 += c2 * cw1[h * 3 + 0];
        a1 += c2 * cw1[h * 3 + 1];
        a2 += c2 * cw1[h * 3 + 2];
        cc += c2 * cb1[h];
    }
    cc += cb2[0];
    const float r = RATE_F / (float)batch_num[0];

    // ---- per-batch dot + sum partials, all in registers (v is L1/L2-hot) --
    const float4* v4 = (const float4*)vin;   // (8, 256) float4
    float acc[8], sv[8], s2[8];
    #pragma unroll
    for (int b = 0; b < 8; b++) {
        const float4 v0 = v4[b * 256 + ia], v1 = v4[b * 256 + ia + 1];
        const float4 v2 = v4[b * 256 + ib], v3 = v4[b * 256 + ib + 1];
        acc[b] = w0.x * v0.x + w0.y * v0.y + w0.z * v0.z + w0.w * v0.w
               + w1.x * v1.x + w1.y * v1.y + w1.z * v1.z + w1.w * v1.w
               + w2.x * v2.x + w2.y * v2.y + w2.z * v2.z + w2.w * v2.w
               + w3.x * v3.x + w3.y * v3.y + w3.z * v3.z + w3.w * v3.w;
        sv[b]  = v0.x + v0.y + v0.z + v0.w + v1.x + v1.y + v1.z + v1.w
               + v2.x + v2.y + v2.z + v2.w + v3.x + v3.y + v3.z + v3.w;
        s2[b]  = v0.x * v0.x + v0.y * v0.y + v0.z * v0.z + v0.w * v0.w
               + v1.x * v1.x + v1.y * v1.y + v1.z * v1.z + v1.w * v1.w
               + v2.x * v2.x + v2.y * v2.y + v2.z * v2.z + v2.w * v2.w
               + v3.x * v3.x + v3.y * v3.y + v3.z * v3.z + v3.w * v3.w;
    }

    // ---- butterfly all-reduce across the wave ----
    #pragma unroll
    for (int b = 0; b < 8; b++) {
        #pragma unroll
        for (int m = 32; m >= 1; m >>= 1) {
            acc[b] += __shfl_xor(acc[b], m, 64);
            sv[b]  += __shfl_xor(sv[b],  m, 64);
            s2[b]  += __shfl_xor(s2[b],  m, 64);
        }
    }

    // ---- epilogue: lane b writes batch b ----
    if (lane < 8) {
        float dot = 0.f, svv = 0.f, s2v = 0.f;
        #pragma unroll
        for (int b = 0; b < 8; b++)
            if (lane == b) { dot = acc[b]; svv = sv[b]; s2v = s2[b]; }
        float vj = dot + bo;
        vj = vj > 0.f ? vj : 0.f;
        const float outv = vj + r * (a0 * s2v + a1 * dot
                                     + (a2 * vj + cc) * svv);
        vout[(size_t)lane * n_out + o] = outv;
    }
}

extern "C" void kernel_launch(void* const* d_in, const int* in_sizes, int n_in,
                              void* d_out, int out_size, void* d_ws, size_t ws_size,
                              hipStream_t stream) {
    const float* x   = (const float*)d_in[0];
    const float* W1  = (const float*)d_in[1];
    const float* b1  = (const float*)d_in[2];
    const float* W2  = (const float*)d_in[3];
    const float* b2  = (const float*)d_in[4];
    const float* W3  = (const float*)d_in[5];
    const float* b3  = (const float*)d_in[6];
    const float* cw1 = (const float*)d_in[7];
    const float* cb1 = (const float*)d_in[8];
    const float* cw2 = (const float*)d_in[9];
    const float* cb2 = (const float*)d_in[10];
    const int*   bn  = (const int*)d_in[11];

    float* v1 = (float*)d_ws;         // 8x1024 fp32 intermediate
    float* v2 = v1 + 8 * 1024;        // 8x1024 fp32 intermediate

    hebb_layer<<<256, 256, 0, stream>>>(x,  W1, b1, cw1, cb1, cw2, cb2, bn, v1, 1024);
    hebb_layer<<<256, 256, 0, stream>>>(v1, W2, b2, cw1, cb1, cw2, cb2, bn, v2, 1024);
    hebb_layer<<<128, 256, 0, stream>>>(v2, W3, b3, cw1, cb1, cw2, cb2, bn, (float*)d_out, 512);
}